// Round 3
// baseline (190.185 us; speedup 1.0000x reference)
//
#include <hip/hip_runtime.h>
#include <math.h>

#define Bsz 128
#define Usz 16
#define Dsz 256
#define Nsz 1024
#define Osz 256
#define BK  64

typedef __attribute__((ext_vector_type(2))) unsigned int u32x2;
typedef __attribute__((ext_vector_type(4))) unsigned int u32x4;
typedef __attribute__((ext_vector_type(4))) float f32x4;
typedef __attribute__((ext_vector_type(8))) short bf16x8;

union cell_u { u32x4 u; bf16x8 b; };

__device__ __forceinline__ unsigned int fbits(float f) {
    union { float f; unsigned int u; } v; v.f = f; return v.u;
}
// pack two f32 -> (bf16(hi)<<16)|bf16(lo) by truncation: 1 v_perm_b32
__device__ __forceinline__ unsigned int pk(float lo, float hi) {
    return __builtin_amdgcn_perm(fbits(hi), fbits(lo), 0x07060302u);
}
__device__ __forceinline__ u32x2 pk4(f32x4 v, float s) {
    v *= s;
    u32x2 r; r[0] = pk(v[0], v[1]); r[1] = pk(v[2], v[3]);
    return r;
}
// 8 k-strided scalar loads -> bf16x8 B-fragment (lane: n fixed, k contiguous)
__device__ __forceinline__ bf16x8 ldB8(const float* p, size_t str) {
    const float x0 = p[0],       x1 = p[str],     x2 = p[2*str], x3 = p[3*str];
    const float x4 = p[4*str],   x5 = p[5*str],   x6 = p[6*str], x7 = p[7*str];
    cell_u r;
    r.u[0] = pk(x0, x1); r.u[1] = pk(x2, x3);
    r.u[2] = pk(x4, x5); r.u[3] = pk(x6, x7);
    return r.b;
}

// Barrier WITHOUT the vmcnt(0) drain that __syncthreads() emits.
// All in-flight global loads here target REGISTERS (ra/rb), so the barrier
// only needs LDS-op visibility: lgkmcnt(0) + s_barrier. Register data
// hazards (ra->wrA, rb->MFMA) are enforced by the compiler's own counted
// s_waitcnt at the point of use -> prefetches survive the barrier (T4).
// Form: inline-asm waitcnt + builtin barrier (the 8-phase-template idiom).
__device__ __forceinline__ void block_sync_nodrain() {
    asm volatile("s_waitcnt lgkmcnt(0)" ::: "memory");
    __builtin_amdgcn_s_barrier();
}

// ---------------- lr = softmax_u(X·alr / T) ----------------
__global__ __launch_bounds__(256)
void lr_kernel(const float* __restrict__ X, const float* __restrict__ alr,
               const float* __restrict__ temp, float* __restrict__ lr)
{
    const int b = blockIdx.x;
    const int t = threadIdx.x;
    const int u = t >> 4;
    const int l = t & 15;
    const float* xp = X + ((size_t)b * Usz + u) * Dsz;
    const float* ap = alr + (size_t)u * Dsz;
    float s = 0.f;
    for (int d = l; d < Dsz; d += 16) s += xp[d] * ap[d];
    s += __shfl_down(s, 8, 16);
    s += __shfl_down(s, 4, 16);
    s += __shfl_down(s, 2, 16);
    s += __shfl_down(s, 1, 16);
    __shared__ float logits[16];
    if (l == 0) logits[u] = s;
    __syncthreads();
    if (t < 16) {
        const float T = temp[0];
        float m = -1e30f;
        #pragma unroll
        for (int i = 0; i < 16; i++) m = fmaxf(m, logits[i] / T);
        float sum = 0.f;
        #pragma unroll
        for (int i = 0; i < 16; i++) sum += expf(logits[i] / T - m);
        lr[(size_t)b * Usz + t] = expf(logits[t] / T - m) / sum;
    }
}

// ---- state GEMM: C = [X | state*sr] · [Win ; W], K=1280, epilogue fused ----
// v3: same tiling as v2 (N-tile 32, grid 512 = nt32 x u16, reg-prefetched B
// dist 1, LDS-staged A dist 1) but the per-step __syncthreads() -> raw
// s_barrier + lgkmcnt(0) only. v1/v2 showed time-per-step pinned at ~2.85us
// regardless of occupancy: the vmcnt(0) drain at each barrier was the
// serializer. Loads now stay in flight across the barrier.
__global__ __launch_bounds__(256)
void state_gemm(const float* __restrict__ X, const float* __restrict__ state,
                const float* __restrict__ W, const float* __restrict__ Win,
                const float* __restrict__ bias, const float* __restrict__ sr,
                const float* __restrict__ lr, float* __restrict__ out0)
{
    const int id = blockIdx.x;       // 512 = u16 x nt32
    const int u  = id & 15;
    const int nt = id >> 4;          // 0..31

    const int tid  = threadIdx.x;
    const int wave = tid >> 6, lane = tid & 63;
    const int l16  = lane & 15, kgl = lane >> 4;
    const int wm = wave & 1, wn = wave >> 1;   // wm: m-half, wn: n-half (16 cols)

    // A LDS: [m128][k64 + pad8] bf16, x2 buffers = 36 KB  (2 blocks/CU fit)
    __shared__ unsigned short As[2][128 * 72];

    const float sru = sr[u];

    // staging map: thread (r0 = tid>>4, c = tid&15); loads rows r0+16i,
    // 16B k-seg c. One wave-instr = 4 rows x full 256B row-step = 8 lines.
    const int r0 = tid >> 4;
    const int c  = tid & 15;

    f32x4 ra[8];   // next-step A tile slice (constant-indexed -> VGPRs)

    auto ldA = [&](int s) {
        const int k0 = s * BK;
        if (k0 < Dsz) {
            const float* base = X + ((size_t)r0 * Usz + u) * Dsz + k0 + c * 4;
            #pragma unroll
            for (int i = 0; i < 8; i++)
                ra[i] = *(const f32x4*)(base + (size_t)16 * i * Usz * Dsz);
        } else {
            const float* base = state + ((size_t)r0 * Usz + u) * Nsz + (k0 - Dsz) + c * 4;
            #pragma unroll
            for (int i = 0; i < 8; i++)
                ra[i] = *(const f32x4*)(base + (size_t)16 * i * Usz * Nsz);
        }
    };
    auto wrA = [&](int p, float sc) {
        #pragma unroll
        for (int i = 0; i < 8; i++)
            *(u32x2*)&As[p][(r0 + 16 * i) * 72 + c * 4] = pk4(ra[i], sc);
    };

    const int col = nt * 32 + wn * 16 + l16;

    cell_u rb0[2], rb1[2];   // B fragment double-buffer (static-indexed)
    auto ldBf = [&](int s, cell_u rb[2]) {
        const int k0 = s * BK;
        const float* bbase = (k0 < Dsz)
            ? Win + (size_t)u * Dsz * Nsz + (size_t)k0 * Nsz
            : W   + (size_t)u * Nsz * Nsz + (size_t)(k0 - Dsz) * Nsz;
        #pragma unroll
        for (int kk = 0; kk < 2; kk++)
            rb[kk].b = ldB8(bbase + (size_t)(kk * 32 + kgl * 8) * Nsz + col, Nsz);
    };

    f32x4 acc[4] = {};
    auto comp = [&](int p, cell_u rb[2]) {
        #pragma unroll
        for (int kk = 0; kk < 2; kk++) {
            #pragma unroll
            for (int mi = 0; mi < 4; mi++) {
                const bf16x8 af = *(const bf16x8*)&As[p][(wm * 64 + mi * 16 + l16) * 72 + kk * 32 + kgl * 8];
                acc[mi] = __builtin_amdgcn_mfma_f32_16x16x32_bf16(af, rb[kk].b, acc[mi], 0, 0, 0);
            }
        }
    };

    ldA(0); wrA(0, 1.f);
    ldBf(0, rb0);
    ldA(1);
    block_sync_nodrain();
    for (int s2 = 0; s2 < 10; s2++) {
        const int s = 2 * s2;
        // even step s: LDS buf0 + rb0; prefetch step s+1 into buf1/rb1
        ldBf(s + 1, rb1);                       // B loads issue first (hide latency)
        wrA(1, (s + 1 < 4) ? 1.f : sru);        // ra holds step s+1
        if (s + 2 < 20) ldA(s + 2);
        comp(0, rb0);
        block_sync_nodrain();
        // odd step s+1: LDS buf1 + rb1; prefetch step s+2 into buf0/rb0
        if (s + 2 < 20) {
            ldBf(s + 2, rb0);
            wrA(0, (s + 2 < 4) ? 1.f : sru);    // ra holds step s+2
            ldA(s + 3);                         // s even<=16 -> s+3<=19 in-range
        }
        comp(1, rb1);
        block_sync_nodrain();
    }

    // C/D layout: col=lane&15, row=(lane>>4)*4+reg (HW-verified)
    const int gcol = nt * 32 + wn * 16 + l16;
    const float bi = bias[u * Nsz + gcol];
    #pragma unroll
    for (int mi = 0; mi < 4; mi++) {
        #pragma unroll
        for (int rg = 0; rg < 4; rg++) {
            const int grow = wm * 64 + mi * 16 + kgl * 4 + rg;
            const size_t idx = ((size_t)grow * Usz + u) * Nsz + gcol;
            const float th = tanhf(acc[mi][rg] + bi);
            const float lv = lr[grow * Usz + u];
            out0[idx] = (1.f - lv) * state[idx] + lv * th;
        }
    }
}

// ---- out GEMM: ns(128xK=1024) · Wout(Kx256), same v3 structure, split-K ----
// grid = ks x ot8 x u16; each block: M128 x N32, nsteps K-steps of 64.
__global__ __launch_bounds__(256)
void out_gemm(const float* __restrict__ ns, const float* __restrict__ Wout,
              float* __restrict__ dst, int nsteps, int partial)
{
    const int id = blockIdx.x;
    const int u  = id & 15;
    const int ot = (id >> 4) & 7;
    const int ks = id >> 7;
    const int kbase = ks * nsteps * BK;

    const int tid  = threadIdx.x;
    const int wave = tid >> 6, lane = tid & 63;
    const int l16  = lane & 15, kgl = lane >> 4;
    const int wm = wave & 1, wn = wave >> 1;

    __shared__ unsigned short As[2][128 * 72];

    const int r0 = tid >> 4;
    const int c  = tid & 15;

    f32x4 ra[8];
    auto ldA = [&](int s) {
        const float* base = ns + ((size_t)r0 * Usz + u) * Nsz + kbase + s * BK + c * 4;
        #pragma unroll
        for (int i = 0; i < 8; i++)
            ra[i] = *(const f32x4*)(base + (size_t)16 * i * Usz * Nsz);
    };
    auto wrA = [&](int p) {
        #pragma unroll
        for (int i = 0; i < 8; i++)
            *(u32x2*)&As[p][(r0 + 16 * i) * 72 + c * 4] = pk4(ra[i], 1.f);
    };

    const int col = ot * 32 + wn * 16 + l16;

    cell_u rb0[2], rb1[2];
    auto ldBf = [&](int s, cell_u rb[2]) {
        const float* bbase = Wout + (size_t)u * Nsz * Osz + (size_t)(kbase + s * BK) * Osz;
        #pragma unroll
        for (int kk = 0; kk < 2; kk++)
            rb[kk].b = ldB8(bbase + (size_t)(kk * 32 + kgl * 8) * Osz + col, Osz);
    };

    f32x4 acc[4] = {};
    auto comp = [&](int p, cell_u rb[2]) {
        #pragma unroll
        for (int kk = 0; kk < 2; kk++) {
            #pragma unroll
            for (int mi = 0; mi < 4; mi++) {
                const bf16x8 af = *(const bf16x8*)&As[p][(wm * 64 + mi * 16 + l16) * 72 + kk * 32 + kgl * 8];
                acc[mi] = __builtin_amdgcn_mfma_f32_16x16x32_bf16(af, rb[kk].b, acc[mi], 0, 0, 0);
            }
        }
    };

    ldA(0); wrA(0);
    ldBf(0, rb0);
    if (nsteps > 1) ldA(1);
    block_sync_nodrain();
    for (int s2 = 0; s2 < nsteps / 2; s2++) {
        const int s = 2 * s2;
        ldBf(s + 1, rb1);
        wrA(1);
        if (s + 2 < nsteps) ldA(s + 2);
        comp(0, rb0);
        block_sync_nodrain();
        if (s + 2 < nsteps) {
            ldBf(s + 2, rb0);
            wrA(0);
            ldA(s + 3);   // even s <= nsteps-4 -> s+3 <= nsteps-1 in-range
        }
        comp(1, rb1);
        block_sync_nodrain();
    }

    const int gcol = ot * 32 + wn * 16 + l16;
    #pragma unroll
    for (int mi = 0; mi < 4; mi++) {
        #pragma unroll
        for (int rg = 0; rg < 4; rg++) {
            const int grow = wm * 64 + mi * 16 + kgl * 4 + rg;
            if (partial)
                dst[(((size_t)ks * 16 + u) * 128 + grow) * 256 + gcol] = acc[mi][rg];
            else
                dst[((size_t)grow * Usz + u) * Osz + gcol] = acc[mi][rg];
        }
    }
}

// ---- sum 4 out-partials -> out1. 512 blocks x 256 thr ----
__global__ __launch_bounds__(256)
void out_reduce(const float* __restrict__ part, float* __restrict__ out1)
{
    const size_t i = (size_t)blockIdx.x * 256 + threadIdx.x;   // 0..131071
    const size_t base = i * 4;                 // flat [m][u][o]
    const int m = (int)(base >> 12);
    const int u = (int)((base >> 8) & 15);
    const int o = (int)(base & 255);

    const size_t pb = ((size_t)u * 128 + m) * 256 + o;
    const size_t slab = (size_t)16 * 128 * 256;
    f32x4 s = *(const f32x4*)(part + pb);
    s += *(const f32x4*)(part + pb + slab);
    s += *(const f32x4*)(part + pb + 2 * slab);
    s += *(const f32x4*)(part + pb + 3 * slab);
    *(f32x4*)(out1 + base) = s;
}

extern "C" void kernel_launch(void* const* d_in, const int* in_sizes, int n_in,
                              void* d_out, int out_size, void* d_ws, size_t ws_size,
                              hipStream_t stream)
{
    (void)in_sizes; (void)n_in; (void)out_size;
    const float* X     = (const float*)d_in[0];
    const float* state = (const float*)d_in[1];
    const float* W     = (const float*)d_in[2];
    const float* Win   = (const float*)d_in[3];
    const float* bias  = (const float*)d_in[4];
    const float* Wout  = (const float*)d_in[5];
    const float* sr    = (const float*)d_in[6];
    const float* alr   = (const float*)d_in[7];
    const float* temp  = (const float*)d_in[8];

    float* out0 = (float*)d_out;                      // (B,U,N)
    float* out1 = out0 + (size_t)Bsz * Usz * Nsz;     // (B,U,O)
    float* lr   = (float*)d_ws;                       // 8 KB

    const size_t p_off   = 8192;
    const size_t p_bytes = (size_t)4 * 16 * 128 * 256 * 4;   // 8 MiB

    lr_kernel<<<Bsz, 256, 0, stream>>>(X, alr, temp, lr);
    state_gemm<<<512, 256, 0, stream>>>(X, state, W, Win, bias, sr, lr, out0);

    if (ws_size >= p_off + p_bytes) {
        float* part = (float*)((char*)d_ws + p_off);
        out_gemm<<<512, 256, 0, stream>>>(out0, Wout, part, 4, 1);    // ks4 x ot8 x u16
        out_reduce<<<512, 256, 0, stream>>>(part, out1);
    } else {
        out_gemm<<<128, 256, 0, stream>>>(out0, Wout, out1, 16, 0);   // ks1
    }
}

// Round 4
// 182.234 us; speedup vs baseline: 1.0436x; 1.0436x over previous
//
#include <hip/hip_runtime.h>
#include <math.h>

#define Bsz 128
#define Usz 16
#define Dsz 256
#define Nsz 1024
#define Osz 256
#define BK  64

typedef __attribute__((ext_vector_type(2))) unsigned int u32x2;
typedef __attribute__((ext_vector_type(4))) unsigned int u32x4;
typedef __attribute__((ext_vector_type(4))) float f32x4;
typedef __attribute__((ext_vector_type(8))) short bf16x8;

union cell_u { u32x4 u; bf16x8 b; };

__device__ __forceinline__ unsigned int fbits(float f) {
    union { float f; unsigned int u; } v; v.f = f; return v.u;
}
// pack two f32 -> (bf16(hi)<<16)|bf16(lo) by truncation: 1 v_perm_b32
__device__ __forceinline__ unsigned int pk(float lo, float hi) {
    return __builtin_amdgcn_perm(fbits(hi), fbits(lo), 0x07060302u);
}
__device__ __forceinline__ u32x2 pk4(f32x4 v, float s) {
    v *= s;
    u32x2 r; r[0] = pk(v[0], v[1]); r[1] = pk(v[2], v[3]);
    return r;
}
// 8 k-strided scalar loads -> bf16x8 B-fragment (lane: n fixed, k contiguous)
__device__ __forceinline__ bf16x8 ldB8(const float* p, size_t str) {
    const float x0 = p[0],       x1 = p[str],     x2 = p[2*str], x3 = p[3*str];
    const float x4 = p[4*str],   x5 = p[5*str],   x6 = p[6*str], x7 = p[7*str];
    cell_u r;
    r.u[0] = pk(x0, x1); r.u[1] = pk(x2, x3);
    r.u[2] = pk(x4, x5); r.u[3] = pk(x6, x7);
    return r.b;
}

// Barrier WITHOUT the vmcnt(0) drain. v3's version had ::: "memory" on the
// asm -> SIInsertWaitcnts treats it as may-alias-all-memory and drains
// vmcnt(0) anyway (v3 measured EXACTLY == v2). Correct idiom per the
// 8-phase template (T4) + rule #18: un-clobbered waitcnt asm, ordered by
// sched_barrier(0), + builtin s_barrier (which does NOT get a compiler
// vmcnt(0) -- m194-m199 verified). Global loads (reg-targeted) stay in
// flight; only the compiler's counted register-dependency waits remain.
__device__ __forceinline__ void sync_nodrain() {
    __builtin_amdgcn_sched_barrier(0);
    asm volatile("s_waitcnt lgkmcnt(0)");
    __builtin_amdgcn_sched_barrier(0);
    __builtin_amdgcn_s_barrier();
    __builtin_amdgcn_sched_barrier(0);
}

// ---------------- lr = softmax_u(X·alr / T) ----------------
__global__ __launch_bounds__(256)
void lr_kernel(const float* __restrict__ X, const float* __restrict__ alr,
               const float* __restrict__ temp, float* __restrict__ lr)
{
    const int b = blockIdx.x;
    const int t = threadIdx.x;
    const int u = t >> 4;
    const int l = t & 15;
    const float* xp = X + ((size_t)b * Usz + u) * Dsz;
    const float* ap = alr + (size_t)u * Dsz;
    float s = 0.f;
    for (int d = l; d < Dsz; d += 16) s += xp[d] * ap[d];
    s += __shfl_down(s, 8, 16);
    s += __shfl_down(s, 4, 16);
    s += __shfl_down(s, 2, 16);
    s += __shfl_down(s, 1, 16);
    __shared__ float logits[16];
    if (l == 0) logits[u] = s;
    __syncthreads();
    if (t < 16) {
        const float T = temp[0];
        float m = -1e30f;
        #pragma unroll
        for (int i = 0; i < 16; i++) m = fmaxf(m, logits[i] / T);
        float sum = 0.f;
        #pragma unroll
        for (int i = 0; i < 16; i++) sum += expf(logits[i] / T - m);
        lr[(size_t)b * Usz + t] = expf(logits[t] / T - m) / sum;
    }
}

// ---- state GEMM: C = [X | state*sr] · [Win ; W], K=1280, epilogue fused ----
// v4: N-tile 32, grid 512 = nt32 x u16 (2 blocks/CU). Pipeline:
//   even step s entry: LDS buf0=A(s), rb0=B(s), raE=A(s+1) in regs.
//   body: ldBf(s+1->rb1); ldA(s+2->raO); wrA(buf1<-raE); comp(buf0,rb0); sync
// ra double-buffered (raE/raO) -> A load->ds_write distance = 2 steps;
// B reg-prefetch distance = 1 step. sync has NO vmcnt drain.
__global__ __launch_bounds__(256)
void state_gemm(const float* __restrict__ X, const float* __restrict__ state,
                const float* __restrict__ W, const float* __restrict__ Win,
                const float* __restrict__ bias, const float* __restrict__ sr,
                const float* __restrict__ lr, float* __restrict__ out0)
{
    const int id = blockIdx.x;       // 512 = u16 x nt32
    const int u  = id & 15;
    const int nt = id >> 4;          // 0..31

    const int tid  = threadIdx.x;
    const int wave = tid >> 6, lane = tid & 63;
    const int l16  = lane & 15, kgl = lane >> 4;
    const int wm = wave & 1, wn = wave >> 1;   // wm: m-half, wn: n-half (16 cols)

    // A LDS: [m128][k64 + pad8] bf16, x2 buffers = 36 KB
    __shared__ unsigned short As[2][128 * 72];

    const float sru = sr[u];

    // staging map: thread (r0 = tid>>4, c = tid&15); loads rows r0+16i,
    // 16B k-seg c. One wave-instr = 4 rows x 256B = 8 lines.
    const int r0 = tid >> 4;
    const int c  = tid & 15;

    f32x4 raE[8], raO[8];   // A-prefetch double buffer (static-indexed)

    auto ldA = [&](int s, f32x4 (&ra)[8]) {
        const int k0 = s * BK;
        if (k0 < Dsz) {
            const float* base = X + ((size_t)r0 * Usz + u) * Dsz + k0 + c * 4;
            #pragma unroll
            for (int i = 0; i < 8; i++)
                ra[i] = *(const f32x4*)(base + (size_t)16 * i * Usz * Dsz);
        } else {
            const float* base = state + ((size_t)r0 * Usz + u) * Nsz + (k0 - Dsz) + c * 4;
            #pragma unroll
            for (int i = 0; i < 8; i++)
                ra[i] = *(const f32x4*)(base + (size_t)16 * i * Usz * Nsz);
        }
    };
    auto wrA = [&](int p, f32x4 (&ra)[8], float sc) {
        #pragma unroll
        for (int i = 0; i < 8; i++)
            *(u32x2*)&As[p][(r0 + 16 * i) * 72 + c * 4] = pk4(ra[i], sc);
    };

    const int col = nt * 32 + wn * 16 + l16;

    cell_u rb0[2], rb1[2];   // B fragment double-buffer (static-indexed)
    auto ldBf = [&](int s, cell_u rb[2]) {
        const int k0 = s * BK;
        const float* bbase = (k0 < Dsz)
            ? Win + (size_t)u * Dsz * Nsz + (size_t)k0 * Nsz
            : W   + (size_t)u * Nsz * Nsz + (size_t)(k0 - Dsz) * Nsz;
        #pragma unroll
        for (int kk = 0; kk < 2; kk++)
            rb[kk].b = ldB8(bbase + (size_t)(kk * 32 + kgl * 8) * Nsz + col, Nsz);
    };

    f32x4 acc[4] = {};
    auto comp = [&](int p, cell_u rb[2]) {
        #pragma unroll
        for (int kk = 0; kk < 2; kk++) {
            #pragma unroll
            for (int mi = 0; mi < 4; mi++) {
                const bf16x8 af = *(const bf16x8*)&As[p][(wm * 64 + mi * 16 + l16) * 72 + kk * 32 + kgl * 8];
                acc[mi] = __builtin_amdgcn_mfma_f32_16x16x32_bf16(af, rb[kk].b, acc[mi], 0, 0, 0);
            }
        }
    };

    // prologue: establish buf0=A(0), rb0=B(0), raE=A(1)
    ldA(0, raO);
    ldBf(0, rb0);
    ldA(1, raE);
    wrA(0, raO, 1.f);
    sync_nodrain();

    for (int s2 = 0; s2 < 10; s2++) {
        const int s = 2 * s2;
        // even step s: consume buf0/rb0
        ldBf(s + 1, rb1);
        if (s + 2 < 20) ldA(s + 2, raO);
        wrA(1, raE, (s + 1 < 4) ? 1.f : sru);        // A(s+1) -> buf1
        comp(0, rb0);
        sync_nodrain();
        // odd step s+1: consume buf1/rb1
        if (s + 2 < 20) {
            ldBf(s + 2, rb0);
            if (s + 3 < 20) ldA(s + 3, raE);
            wrA(0, raO, (s + 2 < 4) ? 1.f : sru);    // A(s+2) -> buf0
        }
        comp(1, rb1);
        sync_nodrain();
    }

    // C/D layout: col=lane&15, row=(lane>>4)*4+reg (HW-verified)
    const int gcol = nt * 32 + wn * 16 + l16;
    const float bi = bias[u * Nsz + gcol];
    #pragma unroll
    for (int mi = 0; mi < 4; mi++) {
        #pragma unroll
        for (int rg = 0; rg < 4; rg++) {
            const int grow = wm * 64 + mi * 16 + kgl * 4 + rg;
            const size_t idx = ((size_t)grow * Usz + u) * Nsz + gcol;
            const float th = tanhf(acc[mi][rg] + bi);
            const float lv = lr[grow * Usz + u];
            out0[idx] = (1.f - lv) * state[idx] + lv * th;
        }
    }
}

// ---- out GEMM: ns(128xK=1024) · Wout(Kx256), same v4 structure, split-K ----
// grid = ks x ot8 x u16; each block: M128 x N32, nsteps K-steps of 64.
__global__ __launch_bounds__(256)
void out_gemm(const float* __restrict__ ns, const float* __restrict__ Wout,
              float* __restrict__ dst, int nsteps, int partial)
{
    const int id = blockIdx.x;
    const int u  = id & 15;
    const int ot = (id >> 4) & 7;
    const int ks = id >> 7;
    const int kbase = ks * nsteps * BK;

    const int tid  = threadIdx.x;
    const int wave = tid >> 6, lane = tid & 63;
    const int l16  = lane & 15, kgl = lane >> 4;
    const int wm = wave & 1, wn = wave >> 1;

    __shared__ unsigned short As[2][128 * 72];

    const int r0 = tid >> 4;
    const int c  = tid & 15;

    f32x4 raE[8], raO[8];
    auto ldA = [&](int s, f32x4 (&ra)[8]) {
        const float* base = ns + ((size_t)r0 * Usz + u) * Nsz + kbase + s * BK + c * 4;
        #pragma unroll
        for (int i = 0; i < 8; i++)
            ra[i] = *(const f32x4*)(base + (size_t)16 * i * Usz * Nsz);
    };
    auto wrA = [&](int p, f32x4 (&ra)[8]) {
        #pragma unroll
        for (int i = 0; i < 8; i++)
            *(u32x2*)&As[p][(r0 + 16 * i) * 72 + c * 4] = pk4(ra[i], 1.f);
    };

    const int col = ot * 32 + wn * 16 + l16;

    cell_u rb0[2], rb1[2];
    auto ldBf = [&](int s, cell_u rb[2]) {
        const float* bbase = Wout + (size_t)u * Nsz * Osz + (size_t)(kbase + s * BK) * Osz;
        #pragma unroll
        for (int kk = 0; kk < 2; kk++)
            rb[kk].b = ldB8(bbase + (size_t)(kk * 32 + kgl * 8) * Osz + col, Osz);
    };

    f32x4 acc[4] = {};
    auto comp = [&](int p, cell_u rb[2]) {
        #pragma unroll
        for (int kk = 0; kk < 2; kk++) {
            #pragma unroll
            for (int mi = 0; mi < 4; mi++) {
                const bf16x8 af = *(const bf16x8*)&As[p][(wm * 64 + mi * 16 + l16) * 72 + kk * 32 + kgl * 8];
                acc[mi] = __builtin_amdgcn_mfma_f32_16x16x32_bf16(af, rb[kk].b, acc[mi], 0, 0, 0);
            }
        }
    };

    // prologue (nsteps is 4 or 16, always even >= 2)
    ldA(0, raO);
    ldBf(0, rb0);
    ldA(1, raE);
    wrA(0, raO);
    sync_nodrain();

    for (int s2 = 0; s2 < nsteps / 2; s2++) {
        const int s = 2 * s2;
        ldBf(s + 1, rb1);
        if (s + 2 < nsteps) ldA(s + 2, raO);
        wrA(1, raE);
        comp(0, rb0);
        sync_nodrain();
        if (s + 2 < nsteps) {
            ldBf(s + 2, rb0);
            if (s + 3 < nsteps) ldA(s + 3, raE);
            wrA(0, raO);
        }
        comp(1, rb1);
        sync_nodrain();
    }

    const int gcol = ot * 32 + wn * 16 + l16;
    #pragma unroll
    for (int mi = 0; mi < 4; mi++) {
        #pragma unroll
        for (int rg = 0; rg < 4; rg++) {
            const int grow = wm * 64 + mi * 16 + kgl * 4 + rg;
            if (partial)
                dst[(((size_t)ks * 16 + u) * 128 + grow) * 256 + gcol] = acc[mi][rg];
            else
                dst[((size_t)grow * Usz + u) * Osz + gcol] = acc[mi][rg];
        }
    }
}

// ---- sum 4 out-partials -> out1. 512 blocks x 256 thr ----
__global__ __launch_bounds__(256)
void out_reduce(const float* __restrict__ part, float* __restrict__ out1)
{
    const size_t i = (size_t)blockIdx.x * 256 + threadIdx.x;   // 0..131071
    const size_t base = i * 4;                 // flat [m][u][o]
    const int m = (int)(base >> 12);
    const int u = (int)((base >> 8) & 15);
    const int o = (int)(base & 255);

    const size_t pb = ((size_t)u * 128 + m) * 256 + o;
    const size_t slab = (size_t)16 * 128 * 256;
    f32x4 s = *(const f32x4*)(part + pb);
    s += *(const f32x4*)(part + pb + slab);
    s += *(const f32x4*)(part + pb + 2 * slab);
    s += *(const f32x4*)(part + pb + 3 * slab);
    *(f32x4*)(out1 + base) = s;
}

extern "C" void kernel_launch(void* const* d_in, const int* in_sizes, int n_in,
                              void* d_out, int out_size, void* d_ws, size_t ws_size,
                              hipStream_t stream)
{
    (void)in_sizes; (void)n_in; (void)out_size;
    const float* X     = (const float*)d_in[0];
    const float* state = (const float*)d_in[1];
    const float* W     = (const float*)d_in[2];
    const float* Win   = (const float*)d_in[3];
    const float* bias  = (const float*)d_in[4];
    const float* Wout  = (const float*)d_in[5];
    const float* sr    = (const float*)d_in[6];
    const float* alr   = (const float*)d_in[7];
    const float* temp  = (const float*)d_in[8];

    float* out0 = (float*)d_out;                      // (B,U,N)
    float* out1 = out0 + (size_t)Bsz * Usz * Nsz;     // (B,U,O)
    float* lr   = (float*)d_ws;                       // 8 KB

    const size_t p_off   = 8192;
    const size_t p_bytes = (size_t)4 * 16 * 128 * 256 * 4;   // 8 MiB

    lr_kernel<<<Bsz, 256, 0, stream>>>(X, alr, temp, lr);
    state_gemm<<<512, 256, 0, stream>>>(X, state, W, Win, bias, sr, lr, out0);

    if (ws_size >= p_off + p_bytes) {
        float* part = (float*)((char*)d_ws + p_off);
        out_gemm<<<512, 256, 0, stream>>>(out0, Wout, part, 4, 1);    // ks4 x ot8 x u16
        out_reduce<<<512, 256, 0, stream>>>(part, out1);
    } else {
        out_gemm<<<128, 256, 0, stream>>>(out0, Wout, out1, 16, 0);   // ks1
    }
}